// Round 1
// 163.085 us; speedup vs baseline: 1.0762x; 1.0762x over previous
//
#include <hip/hip_runtime.h>

// Problem constants (fixed by the reference):
//   x:      (4, 3, 1024, 2048) fp32
//   weight: (3, 3, 3, 3)       fp32   w[o][c][p][q]
//   bn:     (1024, 2048)       int32
//   out:    (4, 3, 1024, 2048) fp32; active region [:, :, :1022, :1022]
//
// Structure exploited (this revision):
//   - gather column index is q in {0,1,2}: only x[:, :, :, 0:3] is ever read
//   - j1 = j % 256 -> pre-mask activation periodic in j with period 256
//   - NEW: for phase-1 columns (j <= 259), bn = floor((cos(a0)-1)*(r-OY))
//     obeys -37 <= bn <= 0  (cos(a0)-1 >= -0.0359, |r-OY| <= 1019.15).
//     Hence gather rows rv = i+p+bn fall in [max(0,i-61), i+2]: a 64-row
//     band. We stage x[c][lo..lo+63][0..3] (3 KB) + bn rows i,i+1 (cols
//     0..259) + bn row i+2 (cols 0..1023) into LDS with ~2.3 coalesced
//     16B loads/thread, then gather from LDS. VMEM instrs/thread: 46 -> ~8.
//     A never-taken global-gather fallback guards the band analysis.
//   - 4096 blocks, one per (b, i) (merged-batch was slower in prior session).
//   - nontemporal f32x4 stores: no L2 write-allocate churn on the 100.7 MB
//     output stream.

#define HH 1024
#define WW 2048
#define HI 1022
#define WJ 1022
#define XSPAN 64

typedef float f32x4 __attribute__((ext_vector_type(4)));
typedef int   i32x4 __attribute__((ext_vector_type(4)));

__global__ __launch_bounds__(256) void dis_conv_kernel(
    const float* __restrict__ x,
    const float* __restrict__ w,
    const int*   __restrict__ bn,
    float*       __restrict__ out)
{
    const int bi = blockIdx.x;      // 0..4095
    const int b  = bi >> 10;        // batch 0..3
    const int i  = bi & 1023;       // output row 0..1023
    const int t  = threadIdx.x;     // 0..255

    __shared__ __align__(16) float v[3][256];        // v[o][jm], jm = j % 256
    __shared__ __align__(16) float xs[3][XSPAN][4];  // x[c][lo+r][0..3]
    __shared__ __align__(16) int   bn01[2][260];     // bn rows i, i+1, cols 0..259
    __shared__ __align__(16) int   bn2[1024];        // bn row i+2,   cols 0..1023

    const bool activeRow = (i < HI);
    const int  lo        = (i > 61) ? (i - 61) : 0;  // x band base row

    // ---- Stage bn + x band into LDS (coalesced 16B loads) ----
    if (activeRow) {
        // bn row i+2, cols 0..1023 (mask + phase-1 p=2)
        ((i32x4*)bn2)[t] = ((const i32x4*)(bn + (size_t)(i + 2) * WW))[t];
        // bn rows i, i+1, cols 0..259
        if (t < 130) {
            const int p = (t >= 65) ? 1 : 0;
            const int k = t - p * 65;
            ((i32x4*)&bn01[p][0])[k] =
                ((const i32x4*)(bn + (size_t)(i + p) * WW))[k];
        }
        // x band: 3 channels x 64 rows x cols 0..3
        if (t < 192) {
            const int c = t >> 6;
            const int r = lo + (t & 63);
            *(f32x4*)&xs[c][t & 63][0] =
                *(const f32x4*)(x + ((size_t)(b * 3 + c) * HH + r) * WW);
        }
    }
    __syncthreads();

    // ---- Phase 1: compute v[o][jm] for this row (jm = t) ----
    float acc0 = 0.f, acc1 = 0.f, acc2 = 0.f;
    if (activeRow) {
        int  rv9[3][3];
        bool ok = true;
        #pragma unroll
        for (int p = 0; p < 3; ++p) {
            #pragma unroll
            for (int q = 0; q < 3; ++q) {
                const int bv = (p < 2) ? bn01[p][t + q] : bn2[t + q];
                const int rv = i + p + bv;
                rv9[p][q] = rv;
                ok &= ((unsigned)(rv - lo) < XSPAN);
            }
        }
        if (__builtin_expect(ok, 1)) {
            // LDS gather path (always taken in practice)
            #pragma unroll
            for (int c = 0; c < 3; ++c) {
                #pragma unroll
                for (int p = 0; p < 3; ++p) {
                    #pragma unroll
                    for (int q = 0; q < 3; ++q) {
                        const float xv = xs[c][rv9[p][q] - lo][q];
                        acc0 += xv * w[(0 * 3 + c) * 9 + p * 3 + q];
                        acc1 += xv * w[(1 * 3 + c) * 9 + p * 3 + q];
                        acc2 += xv * w[(2 * 3 + c) * 9 + p * 3 + q];
                    }
                }
            }
        } else {
            // Safety fallback: direct global gather (numpy negative wrap)
            #pragma unroll
            for (int c = 0; c < 3; ++c) {
                const float* xbase = x + (size_t)(b * 3 + c) * (HH * WW);
                #pragma unroll
                for (int p = 0; p < 3; ++p) {
                    #pragma unroll
                    for (int q = 0; q < 3; ++q) {
                        int rv = rv9[p][q];
                        if (rv < 0)    rv += HH;
                        if (rv >= HH)  rv -= HH;
                        const float xv = xbase[(size_t)rv * WW + q];
                        acc0 += xv * w[(0 * 3 + c) * 9 + p * 3 + q];
                        acc1 += xv * w[(1 * 3 + c) * 9 + p * 3 + q];
                        acc2 += xv * w[(2 * 3 + c) * 9 + p * 3 + q];
                    }
                }
            }
        }
    }
    v[0][t] = acc0;
    v[1][t] = acc1;
    v[2][t] = acc2;
    __syncthreads();

    // ---- Phase 2: mask from LDS bn row, stream 3 output rows ----
    const int   j4 = t * 4;                        // 0..1020
    const f32x4 z  = (f32x4)(0.f);
    f32x4 mm = z;
    if (activeRow) {
        #pragma unroll
        for (int k = 0; k < 4; ++k) {
            const int j = j4 + k;
            mm[k] = (j < WJ && (i + 2) + bn2[j + 2] < HH) ? 1.f : 0.f;
        }
    }
    #pragma unroll
    for (int o = 0; o < 3; ++o) {
        float* orow = out + (((size_t)(b * 3 + o)) * HH + i) * WW;
        const f32x4 vv = *(const f32x4*)&v[o][j4 & 255];
        const f32x4 rv = vv * mm;
        __builtin_nontemporal_store(rv, (f32x4*)&orow[j4]);
        __builtin_nontemporal_store(z,  (f32x4*)&orow[j4 + 1024]);
    }
}

extern "C" void kernel_launch(void* const* d_in, const int* in_sizes, int n_in,
                              void* d_out, int out_size, void* d_ws, size_t ws_size,
                              hipStream_t stream) {
    const float* x   = (const float*)d_in[0];
    const float* w   = (const float*)d_in[1];
    const int*   bn  = (const int*)d_in[2];
    float*       out = (float*)d_out;

    // one block per (b, i) row: 4 * 1024 = 4096 blocks
    dis_conv_kernel<<<dim3(4096), dim3(256), 0, stream>>>(x, w, bn, out);
}